// Round 8
// baseline (1009.260 us; speedup 1.0000x reference)
//
#include <hip/hip_runtime.h>

#define NN    1024
#define STEPS 512
#define RPL   16   // rows per lane; 64 lanes * 16 = 1024 rows = one column per wave

// ---------- complex helpers ----------
__device__ __forceinline__ float2 cmul(float2 p, float2 q) {
    return make_float2(fmaf(p.x, q.x, -p.y * q.y), fmaf(p.x, q.y, p.y * q.x));
}
__device__ __forceinline__ float2 addi(float2 u, float2 v) {
    // u + i*v
    return make_float2(u.x - v.y, u.y + v.x);
}

// ---------- one full step on 16 register-resident rows ----------
// Step = even-MMI, heater(pa), even-MMI, odd-MMI, heater(pb), odd-MMI.
// ca[r] = 0.5 e^{i pa[r]} (heater pa + both even 1/sqrt2 scales).
// cb[r] = 0.5 e^{i pb[r]} interior; rows 0 / N-1 pass through both odd stages,
// so cb is e^{i pb[r]} unscaled there.
__device__ __forceinline__ void do_step(float2 (&m)[RPL],
                                        const float2 (&ca)[RPL],
                                        const float2 (&cb)[RPL],
                                        int t)
{
    // even1 (unscaled Bell): lane-internal pairs (j, j+1), j even
#pragma unroll
    for (int j = 0; j < RPL; j += 2) {
        float2 a = m[j], b = m[j + 1];
        m[j]     = addi(a, b);   // a + i b
        m[j + 1] = addi(b, a);   // i a + b
    }
    // heater(pa) + even2 (scales folded into ca)
#pragma unroll
    for (int j = 0; j < RPL; j += 2) {
        float2 u = cmul(ca[j],     m[j]);
        float2 v = cmul(ca[j + 1], m[j + 1]);
        m[j]     = addi(u, v);
        m[j + 1] = addi(v, u);
    }
    // odd1 (unscaled): pairs (j, j+1), j odd; boundary pair (m[15], next lane's m[0])
    float2 nb, pv;
    nb.x = __shfl_down(m[0].x, 1);        nb.y = __shfl_down(m[0].y, 1);
    pv.x = __shfl_up(m[RPL - 1].x, 1);    pv.y = __shfl_up(m[RPL - 1].y, 1);
#pragma unroll
    for (int j = 1; j < RPL - 1; j += 2) {
        float2 a = m[j], b = m[j + 1];
        m[j]     = addi(a, b);
        m[j + 1] = addi(b, a);
    }
    if (t < 63) m[RPL - 1] = addi(m[RPL - 1], nb);  // row 1023 passes through
    if (t > 0)  m[0]       = addi(m[0], pv);        // row 0    passes through
    // heater(pb) + odd2 (scales folded into cb)
    float2 u0  = cmul(cb[0],       m[0]);
    float2 u15 = cmul(cb[RPL - 1], m[RPL - 1]);
    float2 vn, up;
    vn.x = __shfl_down(u0.x, 1);   vn.y = __shfl_down(u0.y, 1);
    up.x = __shfl_up(u15.x, 1);    up.y = __shfl_up(u15.y, 1);
#pragma unroll
    for (int j = 1; j < RPL - 1; j += 2) {
        float2 u = cmul(cb[j],     m[j]);
        float2 v = cmul(cb[j + 1], m[j + 1]);
        m[j]     = addi(u, v);
        m[j + 1] = addi(v, u);
    }
    m[RPL - 1] = (t < 63) ? addi(u15, vn) : u15;
    m[0]       = (t > 0)  ? addi(u0, up)  : u0;
}

// ---------- shared prologue/epilogue ----------
__device__ __forceinline__ void init_diag(const float* __restrict__ phases,
                                          int c, int r0, float2 (&m)[RPL])
{
    float sv, cv; __sincosf(phases[c], &sv, &cv);
    const float2 diag = make_float2(cv, sv);
#pragma unroll
    for (int j = 0; j < RPL; ++j)
        m[j] = (r0 + j == c) ? diag : make_float2(0.f, 0.f);
}

__device__ __forceinline__ void final_store(const float* __restrict__ phases,
                                            int c, int r0, const float2 (&m)[RPL],
                                            float* __restrict__ outf, int out_size)
{
    // final heater, store REAL PART as float32, row-major [N][N], guarded
    const float* pf = phases + (size_t)(NN + 1) * NN + r0;
#pragma unroll
    for (int j = 0; j < RPL; ++j) {
        float sf, cf; __sincosf(pf[j], &sf, &cf);
        float2 r = cmul(make_float2(cf, sf), m[j]);
        int idx = (r0 + j) * NN + c;
        if (idx < out_size) outf[idx] = r.x;
    }
}

// ========== PATH 1: precomputed constant tables in d_ws ==========
// ca_tab[s][r] = 0.5 e^{i pa_s[r]};  cb_tab[s][r] = (r==0||r==N-1 ? 1 : 0.5) e^{i pb_s[r]}
__global__ void precompute_consts(const float* __restrict__ phases,
                                  float2* __restrict__ ca_tab,
                                  float2* __restrict__ cb_tab)
{
    int idx = blockIdx.x * blockDim.x + threadIdx.x;
    if (idx >= STEPS * NN) return;
    int s = idx >> 10;
    int r = idx & (NN - 1);
    float pa = phases[(size_t)(1 + 2 * s) * NN + r];
    float pb = phases[(size_t)(2 + 2 * s) * NN + r];
    float sa, cA, sb, cB;
    __sincosf(pa, &sa, &cA);
    __sincosf(pb, &sb, &cB);
    ca_tab[idx] = make_float2(0.5f * cA, 0.5f * sa);
    float sc = (r == 0 || r == NN - 1) ? 1.0f : 0.5f;
    cb_tab[idx] = make_float2(sc * cB, sc * sb);
}

__global__ void __launch_bounds__(64, 1)
clements_table(const float* __restrict__ phases,
               const float2* __restrict__ ca_tab,
               const float2* __restrict__ cb_tab,
               float* __restrict__ outf, int out_size)
{
    const int c = blockIdx.x, t = threadIdx.x, r0 = t * RPL;
    float2 m[RPL];
    init_diag(phases, c, r0, m);

    // register double-buffered constants (static indexing via 2-step unroll)
    float2 caA[RPL], cbA[RPL], caB[RPL], cbB[RPL];
    {
        const float2* A0 = ca_tab + r0;
        const float2* B0 = cb_tab + r0;
#pragma unroll
        for (int j = 0; j < RPL; ++j) { caA[j] = A0[j]; cbA[j] = B0[j]; }
    }
    for (int s = 0; s < STEPS; s += 2) {
        {   // prefetch step s+1
            const float2* A1 = ca_tab + (size_t)(s + 1) * NN + r0;
            const float2* B1 = cb_tab + (size_t)(s + 1) * NN + r0;
#pragma unroll
            for (int j = 0; j < RPL; ++j) { caB[j] = A1[j]; cbB[j] = B1[j]; }
        }
        do_step(m, caA, cbA, t);
        {   // prefetch step s+2 (clamped; unused on last iteration)
            int s2 = (s + 2 < STEPS) ? (s + 2) : 0;
            const float2* A2 = ca_tab + (size_t)s2 * NN + r0;
            const float2* B2 = cb_tab + (size_t)s2 * NN + r0;
#pragma unroll
            for (int j = 0; j < RPL; ++j) { caA[j] = A2[j]; cbA[j] = B2[j]; }
        }
        do_step(m, caB, cbB, t);
    }
    final_store(phases, c, r0, m, outf, out_size);
}

// ========== PATH 2: self-contained fallback (no workspace) ==========
__device__ __forceinline__ void load_raw(const float* __restrict__ phases, int s, int r0,
                                         float (&raw)[2 * RPL])
{
    const float* pa = phases + (size_t)(1 + 2 * s) * NN + r0;  // 64B aligned
    const float* pb = pa + NN;
#pragma unroll
    for (int q = 0; q < 4; ++q) {
        float4 v = reinterpret_cast<const float4*>(pa)[q];
        raw[4 * q + 0] = v.x; raw[4 * q + 1] = v.y; raw[4 * q + 2] = v.z; raw[4 * q + 3] = v.w;
    }
#pragma unroll
    for (int q = 0; q < 4; ++q) {
        float4 v = reinterpret_cast<const float4*>(pb)[q];
        raw[RPL + 4 * q + 0] = v.x; raw[RPL + 4 * q + 1] = v.y;
        raw[RPL + 4 * q + 2] = v.z; raw[RPL + 4 * q + 3] = v.w;
    }
}

__device__ __forceinline__ void trig_consts(const float (&raw)[2 * RPL], int r0,
                                            float2 (&ca)[RPL], float2 (&cb)[RPL])
{
#pragma unroll
    for (int j = 0; j < RPL; ++j) {
        float sv, cv; __sincosf(raw[j], &sv, &cv);
        ca[j] = make_float2(0.5f * cv, 0.5f * sv);
    }
#pragma unroll
    for (int j = 0; j < RPL; ++j) {
        float sv, cv; __sincosf(raw[RPL + j], &sv, &cv);
        int gr = r0 + j;
        float sc = (gr == 0 || gr == NN - 1) ? 1.0f : 0.5f;
        cb[j] = make_float2(sc * cv, sc * sv);
    }
}

__global__ void __launch_bounds__(64, 1)
clements_inline(const float* __restrict__ phases,
                float* __restrict__ outf, int out_size)
{
    const int c = blockIdx.x, t = threadIdx.x, r0 = t * RPL;
    float2 m[RPL];
    init_diag(phases, c, r0, m);

    float rawA[2 * RPL], rawB[2 * RPL];
    load_raw(phases, 0, r0, rawA);
    for (int s = 0; s < STEPS; s += 2) {
        load_raw(phases, s + 1, r0, rawB);
        {
            float2 ca[RPL], cb[RPL];
            trig_consts(rawA, r0, ca, cb);
            do_step(m, ca, cb, t);
        }
        load_raw(phases, (s + 2 < STEPS) ? (s + 2) : 0, r0, rawA);
        {
            float2 ca[RPL], cb[RPL];
            trig_consts(rawB, r0, ca, cb);
            do_step(m, ca, cb, t);
        }
    }
    final_store(phases, c, r0, m, outf, out_size);
}

extern "C" void kernel_launch(void* const* d_in, const int* in_sizes, int n_in,
                              void* d_out, int out_size, void* d_ws, size_t ws_size,
                              hipStream_t stream)
{
    (void)in_sizes; (void)n_in;
    const float* phases = (const float*)d_in[0];
    float* outf = (float*)d_out;

    const size_t tabBytes = (size_t)STEPS * NN * sizeof(float2); // 4 MB each
    const bool useTables = (d_ws != nullptr) && (ws_size >= 2 * tabBytes);

    if (useTables) {
        float2* ca_tab = (float2*)d_ws;
        float2* cb_tab = (float2*)((char*)d_ws + tabBytes);
        hipLaunchKernelGGL(precompute_consts,
                           dim3((STEPS * NN + 255) / 256), dim3(256), 0, stream,
                           phases, ca_tab, cb_tab);
        hipLaunchKernelGGL(clements_table, dim3(NN), dim3(64), 0, stream,
                           phases, ca_tab, cb_tab, outf, out_size);
    } else {
        hipLaunchKernelGGL(clements_inline, dim3(NN), dim3(64), 0, stream,
                           phases, outf, out_size);
    }
}

// Round 9
// 954.996 us; speedup vs baseline: 1.0568x; 1.0568x over previous
//
#include <hip/hip_runtime.h>

#define NN    1024
#define STEPS 512
#define RPL   16   // rows per lane; 64 lanes * 16 = 1024 rows = one column per wave

// ---------- complex helpers ----------
__device__ __forceinline__ float2 cmul(float2 p, float2 q) {
    return make_float2(fmaf(p.x, q.x, -p.y * q.y), fmaf(p.x, q.y, p.y * q.x));
}
__device__ __forceinline__ float2 addi(float2 u, float2 v) {
    // u + i*v
    return make_float2(u.x - v.y, u.y + v.x);
}

// ---------- one full step on 16 register-resident rows ----------
// Step = even-MMI, heater(pa), even-MMI, odd-MMI, heater(pb), odd-MMI.
// ca[r] = 0.5 e^{i pa[r]} (heater pa + both even 1/sqrt2 scales).
// cb[r] = 0.5 e^{i pb[r]} interior; rows 0 / N-1 pass through both odd stages,
// so cb is e^{i pb[r]} unscaled there.
__device__ __forceinline__ void do_step(float2 (&m)[RPL],
                                        const float2 (&ca)[RPL],
                                        const float2 (&cb)[RPL],
                                        int t)
{
    // even1 (unscaled Bell): lane-internal pairs (j, j+1), j even
#pragma unroll
    for (int j = 0; j < RPL; j += 2) {
        float2 a = m[j], b = m[j + 1];
        m[j]     = addi(a, b);   // a + i b
        m[j + 1] = addi(b, a);   // i a + b
    }
    // heater(pa) + even2 (scales folded into ca)
#pragma unroll
    for (int j = 0; j < RPL; j += 2) {
        float2 u = cmul(ca[j],     m[j]);
        float2 v = cmul(ca[j + 1], m[j + 1]);
        m[j]     = addi(u, v);
        m[j + 1] = addi(v, u);
    }
    // odd1 (unscaled): pairs (j, j+1), j odd; boundary pair (m[15], next lane's m[0])
    float2 nb, pv;
    nb.x = __shfl_down(m[0].x, 1);        nb.y = __shfl_down(m[0].y, 1);
    pv.x = __shfl_up(m[RPL - 1].x, 1);    pv.y = __shfl_up(m[RPL - 1].y, 1);
#pragma unroll
    for (int j = 1; j < RPL - 1; j += 2) {
        float2 a = m[j], b = m[j + 1];
        m[j]     = addi(a, b);
        m[j + 1] = addi(b, a);
    }
    if (t < 63) m[RPL - 1] = addi(m[RPL - 1], nb);  // row 1023 passes through
    if (t > 0)  m[0]       = addi(m[0], pv);        // row 0    passes through
    // heater(pb) + odd2 (scales folded into cb)
    float2 u0  = cmul(cb[0],       m[0]);
    float2 u15 = cmul(cb[RPL - 1], m[RPL - 1]);
    float2 vn, up;
    vn.x = __shfl_down(u0.x, 1);   vn.y = __shfl_down(u0.y, 1);
    up.x = __shfl_up(u15.x, 1);    up.y = __shfl_up(u15.y, 1);
#pragma unroll
    for (int j = 1; j < RPL - 1; j += 2) {
        float2 u = cmul(cb[j],     m[j]);
        float2 v = cmul(cb[j + 1], m[j + 1]);
        m[j]     = addi(u, v);
        m[j + 1] = addi(v, u);
    }
    m[RPL - 1] = (t < 63) ? addi(u15, vn) : u15;
    m[0]       = (t > 0)  ? addi(u0, up)  : u0;
}

// ---------- shared prologue/epilogue ----------
__device__ __forceinline__ void init_diag(const float* __restrict__ phases,
                                          int c, int r0, float2 (&m)[RPL])
{
    float sv, cv; __sincosf(phases[c], &sv, &cv);
    const float2 diag = make_float2(cv, sv);
#pragma unroll
    for (int j = 0; j < RPL; ++j)
        m[j] = (r0 + j == c) ? diag : make_float2(0.f, 0.f);
}

__device__ __forceinline__ void final_store(const float* __restrict__ phases,
                                            int c, int r0, const float2 (&m)[RPL],
                                            float* __restrict__ outf, int out_size)
{
    // final heater, store REAL PART as float32, row-major [N][N], guarded
    const float* pf = phases + (size_t)(NN + 1) * NN + r0;
#pragma unroll
    for (int j = 0; j < RPL; ++j) {
        float sf, cf; __sincosf(pf[j], &sf, &cf);
        float2 r = cmul(make_float2(cf, sf), m[j]);
        int idx = (r0 + j) * NN + c;
        if (idx < out_size) outf[idx] = r.x;
    }
}

// ---------- vectorized 16-float2 table fragment load ----------
__device__ __forceinline__ void load_tab(const float2* __restrict__ p, float2 (&dst)[RPL])
{
    const float4* p4 = reinterpret_cast<const float4*>(p);  // 16B aligned: r0*8B = 128B multiple
#pragma unroll
    for (int q = 0; q < 8; ++q) {
        float4 v = p4[q];
        dst[2 * q]     = make_float2(v.x, v.y);
        dst[2 * q + 1] = make_float2(v.z, v.w);
    }
}

// ========== PATH 1: precomputed constant tables in d_ws ==========
// ca_tab[s][r] = 0.5 e^{i pa_s[r]};  cb_tab[s][r] = (r==0||r==N-1 ? 1 : 0.5) e^{i pb_s[r]}
__global__ void precompute_consts(const float* __restrict__ phases,
                                  float2* __restrict__ ca_tab,
                                  float2* __restrict__ cb_tab)
{
    int idx = blockIdx.x * blockDim.x + threadIdx.x;
    if (idx >= STEPS * NN) return;
    int s = idx >> 10;
    int r = idx & (NN - 1);
    float pa = phases[(size_t)(1 + 2 * s) * NN + r];
    float pb = phases[(size_t)(2 + 2 * s) * NN + r];
    float sa, cA, sb, cB;
    __sincosf(pa, &sa, &cA);
    __sincosf(pb, &sb, &cB);
    ca_tab[idx] = make_float2(0.5f * cA, 0.5f * sa);
    float sc = (r == 0 || r == NN - 1) ? 1.0f : 0.5f;
    cb_tab[idx] = make_float2(sc * cB, sc * sb);
}

__global__ void __launch_bounds__(64, 1)
clements_table(const float* __restrict__ phases,
               const float2* __restrict__ ca_tab,
               const float2* __restrict__ cb_tab,
               float* __restrict__ outf, int out_size)
{
    const int c = blockIdx.x, t = threadIdx.x, r0 = t * RPL;
    float2 m[RPL];
    init_diag(phases, c, r0, m);

    // register double-buffer; sched_barrier(0) pins the prefetch ISSUE before
    // the compute so the compiler cannot sink the loads to their use (the
    // round-8 failure mode: VGPR=52 proved the buffer had been deleted).
    float2 caA[RPL], cbA[RPL], caB[RPL], cbB[RPL];
    load_tab(ca_tab + r0, caA);
    load_tab(cb_tab + r0, cbA);

    for (int s = 0; s < STEPS; s += 2) {
        // issue prefetch for step s+1, pin it, then compute step s
        load_tab(ca_tab + (size_t)(s + 1) * NN + r0, caB);
        load_tab(cb_tab + (size_t)(s + 1) * NN + r0, cbB);
        __builtin_amdgcn_sched_barrier(0);
        do_step(m, caA, cbA, t);

        // issue prefetch for step s+2 (clamped; value unused on last iter)
        int s2 = (s + 2 < STEPS) ? (s + 2) : 0;
        load_tab(ca_tab + (size_t)s2 * NN + r0, caA);
        load_tab(cb_tab + (size_t)s2 * NN + r0, cbA);
        __builtin_amdgcn_sched_barrier(0);
        do_step(m, caB, cbB, t);
    }
    final_store(phases, c, r0, m, outf, out_size);
}

// ========== PATH 2: self-contained fallback (no workspace) ==========
__global__ void __launch_bounds__(64, 1)
clements_inline(const float* __restrict__ phases,
                float* __restrict__ outf, int out_size)
{
    const int c = blockIdx.x, t = threadIdx.x, r0 = t * RPL;
    float2 m[RPL];
    init_diag(phases, c, r0, m);

    for (int s = 0; s < STEPS; ++s) {
        const float* pa = phases + (size_t)(1 + 2 * s) * NN + r0;
        const float* pb = pa + NN;
        float2 ca[RPL], cb[RPL];
#pragma unroll
        for (int q = 0; q < 4; ++q) {
            float4 va = reinterpret_cast<const float4*>(pa)[q];
            float4 vb = reinterpret_cast<const float4*>(pb)[q];
            float s0, c0;
            __sincosf(va.x, &s0, &c0); ca[4*q + 0] = make_float2(0.5f * c0, 0.5f * s0);
            __sincosf(va.y, &s0, &c0); ca[4*q + 1] = make_float2(0.5f * c0, 0.5f * s0);
            __sincosf(va.z, &s0, &c0); ca[4*q + 2] = make_float2(0.5f * c0, 0.5f * s0);
            __sincosf(va.w, &s0, &c0); ca[4*q + 3] = make_float2(0.5f * c0, 0.5f * s0);
            __sincosf(vb.x, &s0, &c0); cb[4*q + 0] = make_float2(0.5f * c0, 0.5f * s0);
            __sincosf(vb.y, &s0, &c0); cb[4*q + 1] = make_float2(0.5f * c0, 0.5f * s0);
            __sincosf(vb.z, &s0, &c0); cb[4*q + 2] = make_float2(0.5f * c0, 0.5f * s0);
            __sincosf(vb.w, &s0, &c0); cb[4*q + 3] = make_float2(0.5f * c0, 0.5f * s0);
        }
        if (t == 0)  cb[0]       = make_float2(2.f * cb[0].x,       2.f * cb[0].y);
        if (t == 63) cb[RPL - 1] = make_float2(2.f * cb[RPL - 1].x, 2.f * cb[RPL - 1].y);
        do_step(m, ca, cb, t);
    }
    final_store(phases, c, r0, m, outf, out_size);
}

extern "C" void kernel_launch(void* const* d_in, const int* in_sizes, int n_in,
                              void* d_out, int out_size, void* d_ws, size_t ws_size,
                              hipStream_t stream)
{
    (void)in_sizes; (void)n_in;
    const float* phases = (const float*)d_in[0];
    float* outf = (float*)d_out;

    const size_t tabBytes = (size_t)STEPS * NN * sizeof(float2); // 4 MB each
    const bool useTables = (d_ws != nullptr) && (ws_size >= 2 * tabBytes);

    if (useTables) {
        float2* ca_tab = (float2*)d_ws;
        float2* cb_tab = (float2*)((char*)d_ws + tabBytes);
        hipLaunchKernelGGL(precompute_consts,
                           dim3((STEPS * NN + 255) / 256), dim3(256), 0, stream,
                           phases, ca_tab, cb_tab);
        hipLaunchKernelGGL(clements_table, dim3(NN), dim3(64), 0, stream,
                           phases, ca_tab, cb_tab, outf, out_size);
    } else {
        hipLaunchKernelGGL(clements_inline, dim3(NN), dim3(64), 0, stream,
                           phases, outf, out_size);
    }
}

// Round 10
// 570.034 us; speedup vs baseline: 1.7705x; 1.6753x over previous
//
#include <hip/hip_runtime.h>

#define NN    1024
#define STEPS 512

// ---------- complex helpers ----------
__device__ __forceinline__ float2 cmul(float2 p, float2 q) {
    return make_float2(fmaf(p.x, q.x, -p.y * q.y), fmaf(p.x, q.y, p.y * q.x));
}
__device__ __forceinline__ float2 addi(float2 u, float2 v) {
    // u + i*v
    return make_float2(u.x - v.y, u.y + v.x);
}

// ========== precompute per-row step constants (unchanged layout) ==========
// ca_tab[s][r] = 0.5 e^{i pa_s[r]};  cb_tab[s][r] = (r==0||r==N-1 ? 1 : 0.5) e^{i pb_s[r]}
__global__ void precompute_consts(const float* __restrict__ phases,
                                  float2* __restrict__ ca_tab,
                                  float2* __restrict__ cb_tab)
{
    int idx = blockIdx.x * blockDim.x + threadIdx.x;
    if (idx >= STEPS * NN) return;
    int s = idx >> 10;
    int r = idx & (NN - 1);
    float pa = phases[(size_t)(1 + 2 * s) * NN + r];
    float pb = phases[(size_t)(2 + 2 * s) * NN + r];
    float sa, cA, sb, cB;
    __sincosf(pa, &sa, &cA);
    __sincosf(pb, &sb, &cB);
    ca_tab[idx] = make_float2(0.5f * cA, 0.5f * sa);
    float sc = (r == 0 || r == NN - 1) ? 1.0f : 0.5f;
    cb_tab[idx] = make_float2(sc * cB, sc * sb);
}

// ---------- 4-float2 table fragment load (2x float4, 32B aligned) ----------
__device__ __forceinline__ void load4(const float2* __restrict__ p, float2 (&d)[4])
{
    const float4* p4 = reinterpret_cast<const float4*>(p);
    float4 v0 = p4[0], v1 = p4[1];
    d[0] = make_float2(v0.x, v0.y); d[1] = make_float2(v0.z, v0.w);
    d[2] = make_float2(v1.x, v1.y); d[3] = make_float2(v1.z, v1.w);
}

// ---------- one step, 4 rows/lane, cross-wave boundary via LDS ----------
__device__ __forceinline__ void do_step4(float2 (&m)[4],
                                         const float2 (&ca)[4],
                                         const float2 (&cb)[4],
                                         int w, int t, bool firstRow, bool lastRow,
                                         float2* __restrict__ lo1, float2* __restrict__ hi1,
                                         float2* __restrict__ lo2, float2* __restrict__ hi2)
{
    // even1 (unscaled): lane-internal pairs (0,1) (2,3)
    { float2 a = m[0], b = m[1]; m[0] = addi(a, b); m[1] = addi(b, a); }
    { float2 a = m[2], b = m[3]; m[2] = addi(a, b); m[3] = addi(b, a); }
    // heater(pa) + even2 (scales folded into ca)
    { float2 u = cmul(ca[0], m[0]), v = cmul(ca[1], m[1]); m[0] = addi(u, v); m[1] = addi(v, u); }
    { float2 u = cmul(ca[2], m[2]), v = cmul(ca[3], m[3]); m[2] = addi(u, v); m[3] = addi(v, u); }

    // odd1: interior pair (1,2); boundary pair (m[3], next lane/wave m[0])
    if (t == 0)  lo1[w] = m[0];   // exported PRE-update values
    if (t == 63) hi1[w] = m[3];
    __syncthreads();
    float2 nb, pv;
    nb.x = __shfl_down(m[0].x, 1); nb.y = __shfl_down(m[0].y, 1);
    pv.x = __shfl_up  (m[3].x, 1); pv.y = __shfl_up  (m[3].y, 1);
    if (t == 63 && w < 3) nb = lo1[w + 1];
    if (t == 0  && w > 0) pv = hi1[w - 1];
    { float2 a = m[1], b = m[2]; m[1] = addi(a, b); m[2] = addi(b, a); }
    { float2 m3n = lastRow  ? m[3] : addi(m[3], nb);
      float2 m0n = firstRow ? m[0] : addi(m[0], pv);
      m[3] = m3n; m[0] = m0n; }

    // heater(pb) + odd2 (scales folded into cb)
    float2 u0 = cmul(cb[0], m[0]);
    float2 u3 = cmul(cb[3], m[3]);
    if (t == 0)  lo2[w] = u0;
    if (t == 63) hi2[w] = u3;
    __syncthreads();
    float2 vn, up;
    vn.x = __shfl_down(u0.x, 1); vn.y = __shfl_down(u0.y, 1);
    up.x = __shfl_up  (u3.x, 1); up.y = __shfl_up  (u3.y, 1);
    if (t == 63 && w < 3) vn = lo2[w + 1];
    if (t == 0  && w > 0) up = hi2[w - 1];
    { float2 u = cmul(cb[1], m[1]), v = cmul(cb[2], m[2]); m[1] = addi(u, v); m[2] = addi(v, u); }
    m[3] = lastRow  ? u3 : addi(u3, vn);
    m[0] = firstRow ? u0 : addi(u0, up);
}

// ========== main: 1 block (4 waves) per column, 4 rows/lane ==========
__global__ void __launch_bounds__(256, 4)
clements_split(const float* __restrict__ phases,
               const float2* __restrict__ ca_tab,
               const float2* __restrict__ cb_tab,
               float* __restrict__ outf, int out_size)
{
    const int c   = blockIdx.x;        // column
    const int tid = threadIdx.x;
    const int w   = tid >> 6;          // wave 0..3 within block
    const int t   = tid & 63;          // lane
    const int r0  = w * 256 + t * 4;   // first global row of this lane

    __shared__ float2 lo1[4], hi1[4], lo2[4], hi2[4];

    const bool firstRow = (w == 0 && t == 0);
    const bool lastRow  = (w == 3 && t == 63);

    // M0 = heater(I, phases[0]): diagonal
    float2 m[4];
    {
        float sv, cv; __sincosf(phases[c], &sv, &cv);
        const float2 diag = make_float2(cv, sv);
#pragma unroll
        for (int j = 0; j < 4; ++j)
            m[j] = (r0 + j == c) ? diag : make_float2(0.f, 0.f);
    }

    // register double-buffered constants; sched_barrier pins issue-early
    float2 caA[4], cbA[4], caB[4], cbB[4];
    load4(ca_tab + r0, caA);
    load4(cb_tab + r0, cbA);

    for (int s = 0; s < STEPS; s += 2) {
        load4(ca_tab + (size_t)(s + 1) * NN + r0, caB);
        load4(cb_tab + (size_t)(s + 1) * NN + r0, cbB);
        __builtin_amdgcn_sched_barrier(0);
        do_step4(m, caA, cbA, w, t, firstRow, lastRow, lo1, hi1, lo2, hi2);

        int s2 = (s + 2 < STEPS) ? (s + 2) : 0;   // clamped; unused on last iter
        load4(ca_tab + (size_t)s2 * NN + r0, caA);
        load4(cb_tab + (size_t)s2 * NN + r0, cbA);
        __builtin_amdgcn_sched_barrier(0);
        do_step4(m, caB, cbB, w, t, firstRow, lastRow, lo1, hi1, lo2, hi2);
    }

    // final heater, store REAL PART float32, row-major [N][N], guarded
    const float* pf = phases + (size_t)(NN + 1) * NN + r0;
#pragma unroll
    for (int j = 0; j < 4; ++j) {
        float sf, cf; __sincosf(pf[j], &sf, &cf);
        float2 r = cmul(make_float2(cf, sf), m[j]);
        int idx = (r0 + j) * NN + c;
        if (idx < out_size) outf[idx] = r.x;
    }
}

// ========== fallback (no workspace): proven 840us R=16 inline kernel ==========
__device__ __forceinline__ void do_step16(float2 (&m)[16],
                                          const float2 (&ca)[16],
                                          const float2 (&cb)[16],
                                          int t)
{
#pragma unroll
    for (int j = 0; j < 16; j += 2) {
        float2 a = m[j], b = m[j + 1];
        m[j] = addi(a, b); m[j + 1] = addi(b, a);
    }
#pragma unroll
    for (int j = 0; j < 16; j += 2) {
        float2 u = cmul(ca[j], m[j]), v = cmul(ca[j + 1], m[j + 1]);
        m[j] = addi(u, v); m[j + 1] = addi(v, u);
    }
    float2 nb, pv;
    nb.x = __shfl_down(m[0].x, 1);  nb.y = __shfl_down(m[0].y, 1);
    pv.x = __shfl_up(m[15].x, 1);   pv.y = __shfl_up(m[15].y, 1);
#pragma unroll
    for (int j = 1; j < 15; j += 2) {
        float2 a = m[j], b = m[j + 1];
        m[j] = addi(a, b); m[j + 1] = addi(b, a);
    }
    if (t < 63) m[15] = addi(m[15], nb);
    if (t > 0)  m[0]  = addi(m[0], pv);
    float2 u0 = cmul(cb[0], m[0]), u15 = cmul(cb[15], m[15]);
    float2 vn, up;
    vn.x = __shfl_down(u0.x, 1);  vn.y = __shfl_down(u0.y, 1);
    up.x = __shfl_up(u15.x, 1);   up.y = __shfl_up(u15.y, 1);
#pragma unroll
    for (int j = 1; j < 15; j += 2) {
        float2 u = cmul(cb[j], m[j]), v = cmul(cb[j + 1], m[j + 1]);
        m[j] = addi(u, v); m[j + 1] = addi(v, u);
    }
    m[15] = (t < 63) ? addi(u15, vn) : u15;
    m[0]  = (t > 0)  ? addi(u0, up)  : u0;
}

__global__ void __launch_bounds__(64, 1)
clements_inline(const float* __restrict__ phases,
                float* __restrict__ outf, int out_size)
{
    const int c = blockIdx.x, t = threadIdx.x, r0 = t * 16;
    float2 m[16];
    {
        float sv, cv; __sincosf(phases[c], &sv, &cv);
        const float2 diag = make_float2(cv, sv);
#pragma unroll
        for (int j = 0; j < 16; ++j)
            m[j] = (r0 + j == c) ? diag : make_float2(0.f, 0.f);
    }
    for (int s = 0; s < STEPS; ++s) {
        const float* pa = phases + (size_t)(1 + 2 * s) * NN + r0;
        const float* pb = pa + NN;
        float2 ca[16], cb[16];
#pragma unroll
        for (int q = 0; q < 4; ++q) {
            float4 va = reinterpret_cast<const float4*>(pa)[q];
            float4 vb = reinterpret_cast<const float4*>(pb)[q];
            float s0, c0;
            __sincosf(va.x, &s0, &c0); ca[4*q+0] = make_float2(0.5f*c0, 0.5f*s0);
            __sincosf(va.y, &s0, &c0); ca[4*q+1] = make_float2(0.5f*c0, 0.5f*s0);
            __sincosf(va.z, &s0, &c0); ca[4*q+2] = make_float2(0.5f*c0, 0.5f*s0);
            __sincosf(va.w, &s0, &c0); ca[4*q+3] = make_float2(0.5f*c0, 0.5f*s0);
            __sincosf(vb.x, &s0, &c0); cb[4*q+0] = make_float2(0.5f*c0, 0.5f*s0);
            __sincosf(vb.y, &s0, &c0); cb[4*q+1] = make_float2(0.5f*c0, 0.5f*s0);
            __sincosf(vb.z, &s0, &c0); cb[4*q+2] = make_float2(0.5f*c0, 0.5f*s0);
            __sincosf(vb.w, &s0, &c0); cb[4*q+3] = make_float2(0.5f*c0, 0.5f*s0);
        }
        if (t == 0)  cb[0]  = make_float2(2.f * cb[0].x,  2.f * cb[0].y);
        if (t == 63) cb[15] = make_float2(2.f * cb[15].x, 2.f * cb[15].y);
        do_step16(m, ca, cb, t);
    }
    const float* pf = phases + (size_t)(NN + 1) * NN + r0;
#pragma unroll
    for (int j = 0; j < 16; ++j) {
        float sf, cf; __sincosf(pf[j], &sf, &cf);
        float2 r = cmul(make_float2(cf, sf), m[j]);
        int idx = (r0 + j) * NN + c;
        if (idx < out_size) outf[idx] = r.x;
    }
}

extern "C" void kernel_launch(void* const* d_in, const int* in_sizes, int n_in,
                              void* d_out, int out_size, void* d_ws, size_t ws_size,
                              hipStream_t stream)
{
    (void)in_sizes; (void)n_in;
    const float* phases = (const float*)d_in[0];
    float* outf = (float*)d_out;

    const size_t tabBytes = (size_t)STEPS * NN * sizeof(float2); // 4 MB each
    const bool useTables = (d_ws != nullptr) && (ws_size >= 2 * tabBytes);

    if (useTables) {
        float2* ca_tab = (float2*)d_ws;
        float2* cb_tab = (float2*)((char*)d_ws + tabBytes);
        hipLaunchKernelGGL(precompute_consts,
                           dim3((STEPS * NN + 255) / 256), dim3(256), 0, stream,
                           phases, ca_tab, cb_tab);
        hipLaunchKernelGGL(clements_split, dim3(NN), dim3(256), 0, stream,
                           phases, ca_tab, cb_tab, outf, out_size);
    } else {
        hipLaunchKernelGGL(clements_inline, dim3(NN), dim3(64), 0, stream,
                           phases, outf, out_size);
    }
}

// Round 11
// 495.770 us; speedup vs baseline: 2.0357x; 1.1498x over previous
//
#include <hip/hip_runtime.h>

#define NN    1024
#define STEPS 512

// packed-fp32 complex: f2 = (re, im); LLVM lowers f2 arithmetic to v_pk_* on gfx950
typedef float f2 __attribute__((ext_vector_type(2)));

// u + i*v = (u.x - v.y, u.y + v.x) : one v_pk_fma (swizzle+neg fold into op_sel/neg_lo)
__device__ __forceinline__ f2 addi(f2 u, f2 v) {
    f2 vs = __builtin_shufflevector(v, v, 1, 0);   // (v.y, v.x)
    const f2 sgn = {-1.f, 1.f};
    return __builtin_elementwise_fma(vs, sgn, u);
}
// p*q = (p.x q.x - p.y q.y, p.x q.y + p.y q.x) : v_pk_mul + v_pk_fma
__device__ __forceinline__ f2 cmul(f2 p, f2 q) {
    f2 qs  = __builtin_shufflevector(q, q, 1, 0);  // (q.y, q.x)
    f2 pyn = {-p.y, p.y};
    f2 t   = pyn * qs;                             // (-p.y q.y, p.y q.x)
    f2 pxx = {p.x, p.x};
    return __builtin_elementwise_fma(pxx, q, t);
}

// ========== precompute per-row step constants ==========
// ca_tab[s][r] = 0.5 e^{i pa_s[r]};  cb_tab[s][r] = (r==0||r==N-1 ? 1 : 0.5) e^{i pb_s[r]}
__global__ void precompute_consts(const float* __restrict__ phases,
                                  float2* __restrict__ ca_tab,
                                  float2* __restrict__ cb_tab)
{
    int idx = blockIdx.x * blockDim.x + threadIdx.x;
    if (idx >= STEPS * NN) return;
    int s = idx >> 10;
    int r = idx & (NN - 1);
    float pa = phases[(size_t)(1 + 2 * s) * NN + r];
    float pb = phases[(size_t)(2 + 2 * s) * NN + r];
    float sa, cA, sb, cB;
    __sincosf(pa, &sa, &cA);
    __sincosf(pb, &sb, &cB);
    ca_tab[idx] = make_float2(0.5f * cA, 0.5f * sa);
    float sc = (r == 0 || r == NN - 1) ? 1.0f : 0.5f;
    cb_tab[idx] = make_float2(sc * cB, sc * sb);
}

// ---------- loads ----------
__device__ __forceinline__ void load4(const float2* __restrict__ p, f2 (&d)[4])
{
    const float4* p4 = reinterpret_cast<const float4*>(p);  // 32B-aligned (r0 multiple of 4)
    float4 v0 = p4[0], v1 = p4[1];
    d[0] = (f2){v0.x, v0.y}; d[1] = (f2){v0.z, v0.w};
    d[2] = (f2){v1.x, v1.y}; d[3] = (f2){v1.z, v1.w};
}
__device__ __forceinline__ f2 ldf2(const float2* __restrict__ p)
{
    float2 v = *p; return (f2){v.x, v.y};
}

// ---------- one step, 4 rows/lane, ONE barrier ----------
// Halo algebra: odd1 pair (r0+3, r0+4): m3' = m3 + i*nb ; m0'_next = nb + i*m3.
// odd2 needs u0_next = cb_next * m0'_next = cbn * (nb + i*m3pre) -> boundary lane
// computes it locally; ditto u3_prev = cbp * (pv + i*m0pre). So only the PRE-odd1
// m0/m3 cross waves (one export + one barrier); everything else is shfl.
__device__ __forceinline__ void do_step4(f2 (&m)[4],
                                         const f2 (&ca)[4], const f2 (&cb)[4],
                                         f2 cbn, f2 cbp,
                                         int w, int t, bool firstRow, bool lastRow,
                                         f2* __restrict__ lo1, f2* __restrict__ hi1)
{
    // even1 (unscaled): lane-internal pairs (0,1) (2,3)
    { f2 a = m[0], b = m[1]; m[0] = addi(a, b); m[1] = addi(b, a); }
    { f2 a = m[2], b = m[3]; m[2] = addi(a, b); m[3] = addi(b, a); }
    // heater(pa) + even2 (scales folded into ca)
    { f2 u = cmul(ca[0], m[0]), v = cmul(ca[1], m[1]); m[0] = addi(u, v); m[1] = addi(v, u); }
    { f2 u = cmul(ca[2], m[2]), v = cmul(ca[3], m[3]); m[2] = addi(u, v); m[3] = addi(v, u); }

    // single cross-wave exchange of pre-odd1 boundary values
    if (t == 0)  lo1[w] = m[0];
    if (t == 63) hi1[w] = m[3];
    __syncthreads();

    f2 nb, pv;
    nb.x = __shfl_down(m[0].x, 1); nb.y = __shfl_down(m[0].y, 1);
    pv.x = __shfl_up  (m[3].x, 1); pv.y = __shfl_up  (m[3].y, 1);
    if (t == 63 && w < 3) nb = lo1[w + 1];
    if (t == 0  && w > 0) pv = hi1[w - 1];

    f2 m0pre = m[0], m3pre = m[3];

    // odd1
    { f2 a = m[1], b = m[2]; m[1] = addi(a, b); m[2] = addi(b, a); }
    m[3] = lastRow  ? m[3] : addi(m[3], nb);
    m[0] = firstRow ? m[0] : addi(m[0], pv);

    // heater(pb) + odd2 (scales folded into cb)
    f2 u0 = cmul(cb[0], m[0]);
    f2 u3 = cmul(cb[3], m[3]);
    f2 vn, up;
    vn.x = __shfl_down(u0.x, 1); vn.y = __shfl_down(u0.y, 1);
    up.x = __shfl_up  (u3.x, 1); up.y = __shfl_up  (u3.y, 1);
    if (t == 63 && w < 3) vn = cmul(cbn, addi(nb, m3pre));  // u0 of next wave's first lane
    if (t == 0  && w > 0) up = cmul(cbp, addi(pv, m0pre));  // u3 of prev wave's last lane
    { f2 u = cmul(cb[1], m[1]), v = cmul(cb[2], m[2]); m[1] = addi(u, v); m[2] = addi(v, u); }
    m[3] = lastRow  ? u3 : addi(u3, vn);
    m[0] = firstRow ? u0 : addi(u0, up);
}

// ========== main: 1 block (4 waves) per column, 4 rows/lane ==========
__global__ void __launch_bounds__(256, 4)
clements_split(const float* __restrict__ phases,
               const float2* __restrict__ ca_tab,
               const float2* __restrict__ cb_tab,
               float* __restrict__ outf, int out_size)
{
    const int c   = blockIdx.x;
    const int tid = threadIdx.x;
    const int w   = tid >> 6;
    const int t   = tid & 63;
    const int r0  = tid << 2;      // = w*256 + t*4

    __shared__ f2 lo1[2][4], hi1[2][4];   // parity-double-buffered exchange slots

    const bool firstRow = (w == 0 && t == 0);
    const bool lastRow  = (w == 3 && t == 63);
    const bool wantN = (t == 63 && w < 3);   // needs next-wave constant
    const bool wantP = (t == 0  && w > 0);   // needs prev-wave constant

    // M0 = heater(I, phases[0]): diagonal
    f2 m[4];
    {
        float sv, cv; __sincosf(phases[c], &sv, &cv);
        const f2 diag = {cv, sv};
#pragma unroll
        for (int j = 0; j < 4; ++j)
            m[j] = (r0 + j == c) ? diag : (f2){0.f, 0.f};
    }

    // register double-buffered constants; sched_barrier pins issue-early
    f2 caA[4], cbA[4], caB[4], cbB[4];
    f2 cbnA = {1.f, 0.f}, cbpA = {1.f, 0.f}, cbnB = {1.f, 0.f}, cbpB = {1.f, 0.f};
    load4(ca_tab + r0, caA);
    load4(cb_tab + r0, cbA);
    if (wantN) cbnA = ldf2(cb_tab + r0 + 4);
    if (wantP) cbpA = ldf2(cb_tab + r0 - 1);

    for (int s = 0; s < STEPS; s += 2) {
        {
            size_t o1 = (size_t)(s + 1) * NN + r0;
            load4(ca_tab + o1, caB);
            load4(cb_tab + o1, cbB);
            if (wantN) cbnB = ldf2(cb_tab + o1 + 4);
            if (wantP) cbpB = ldf2(cb_tab + o1 - 1);
        }
        __builtin_amdgcn_sched_barrier(0);
        do_step4(m, caA, cbA, cbnA, cbpA, w, t, firstRow, lastRow, lo1[0], hi1[0]);

        {
            int s2 = (s + 2 < STEPS) ? (s + 2) : 0;   // clamped; unused on last iter
            size_t o2 = (size_t)s2 * NN + r0;
            load4(ca_tab + o2, caA);
            load4(cb_tab + o2, cbA);
            if (wantN) cbnA = ldf2(cb_tab + o2 + 4);
            if (wantP) cbpA = ldf2(cb_tab + o2 - 1);
        }
        __builtin_amdgcn_sched_barrier(0);
        do_step4(m, caB, cbB, cbnB, cbpB, w, t, firstRow, lastRow, lo1[1], hi1[1]);
    }

    // final heater, store REAL PART float32, row-major [N][N], guarded
    const float* pf = phases + (size_t)(NN + 1) * NN + r0;
#pragma unroll
    for (int j = 0; j < 4; ++j) {
        float sf, cf; __sincosf(pf[j], &sf, &cf);
        f2 r = cmul((f2){cf, sf}, m[j]);
        int idx = (r0 + j) * NN + c;
        if (idx < out_size) outf[idx] = r.x;
    }
}

// ========== fallback (no workspace): proven R=16 inline kernel ==========
__device__ __forceinline__ void do_step16(f2 (&m)[16], const f2 (&ca)[16],
                                          const f2 (&cb)[16], int t)
{
#pragma unroll
    for (int j = 0; j < 16; j += 2) {
        f2 a = m[j], b = m[j + 1];
        m[j] = addi(a, b); m[j + 1] = addi(b, a);
    }
#pragma unroll
    for (int j = 0; j < 16; j += 2) {
        f2 u = cmul(ca[j], m[j]), v = cmul(ca[j + 1], m[j + 1]);
        m[j] = addi(u, v); m[j + 1] = addi(v, u);
    }
    f2 nb, pv;
    nb.x = __shfl_down(m[0].x, 1);  nb.y = __shfl_down(m[0].y, 1);
    pv.x = __shfl_up(m[15].x, 1);   pv.y = __shfl_up(m[15].y, 1);
#pragma unroll
    for (int j = 1; j < 15; j += 2) {
        f2 a = m[j], b = m[j + 1];
        m[j] = addi(a, b); m[j + 1] = addi(b, a);
    }
    if (t < 63) m[15] = addi(m[15], nb);
    if (t > 0)  m[0]  = addi(m[0], pv);
    f2 u0 = cmul(cb[0], m[0]), u15 = cmul(cb[15], m[15]);
    f2 vn, up;
    vn.x = __shfl_down(u0.x, 1);  vn.y = __shfl_down(u0.y, 1);
    up.x = __shfl_up(u15.x, 1);   up.y = __shfl_up(u15.y, 1);
#pragma unroll
    for (int j = 1; j < 15; j += 2) {
        f2 u = cmul(cb[j], m[j]), v = cmul(cb[j + 1], m[j + 1]);
        m[j] = addi(u, v); m[j + 1] = addi(v, u);
    }
    m[15] = (t < 63) ? addi(u15, vn) : u15;
    m[0]  = (t > 0)  ? addi(u0, up)  : u0;
}

__global__ void __launch_bounds__(64, 1)
clements_inline(const float* __restrict__ phases,
                float* __restrict__ outf, int out_size)
{
    const int c = blockIdx.x, t = threadIdx.x, r0 = t * 16;
    f2 m[16];
    {
        float sv, cv; __sincosf(phases[c], &sv, &cv);
        const f2 diag = {cv, sv};
#pragma unroll
        for (int j = 0; j < 16; ++j)
            m[j] = (r0 + j == c) ? diag : (f2){0.f, 0.f};
    }
    for (int s = 0; s < STEPS; ++s) {
        const float* pa = phases + (size_t)(1 + 2 * s) * NN + r0;
        const float* pb = pa + NN;
        f2 ca[16], cb[16];
#pragma unroll
        for (int q = 0; q < 4; ++q) {
            float4 va = reinterpret_cast<const float4*>(pa)[q];
            float4 vb = reinterpret_cast<const float4*>(pb)[q];
            float s0, c0;
            __sincosf(va.x, &s0, &c0); ca[4*q+0] = (f2){0.5f*c0, 0.5f*s0};
            __sincosf(va.y, &s0, &c0); ca[4*q+1] = (f2){0.5f*c0, 0.5f*s0};
            __sincosf(va.z, &s0, &c0); ca[4*q+2] = (f2){0.5f*c0, 0.5f*s0};
            __sincosf(va.w, &s0, &c0); ca[4*q+3] = (f2){0.5f*c0, 0.5f*s0};
            __sincosf(vb.x, &s0, &c0); cb[4*q+0] = (f2){0.5f*c0, 0.5f*s0};
            __sincosf(vb.y, &s0, &c0); cb[4*q+1] = (f2){0.5f*c0, 0.5f*s0};
            __sincosf(vb.z, &s0, &c0); cb[4*q+2] = (f2){0.5f*c0, 0.5f*s0};
            __sincosf(vb.w, &s0, &c0); cb[4*q+3] = (f2){0.5f*c0, 0.5f*s0};
        }
        if (t == 0)  cb[0]  = 2.f * cb[0];
        if (t == 63) cb[15] = 2.f * cb[15];
        do_step16(m, ca, cb, t);
    }
    const float* pf = phases + (size_t)(NN + 1) * NN + r0;
#pragma unroll
    for (int j = 0; j < 16; ++j) {
        float sf, cf; __sincosf(pf[j], &sf, &cf);
        f2 r = cmul((f2){cf, sf}, m[j]);
        int idx = (r0 + j) * NN + c;
        if (idx < out_size) outf[idx] = r.x;
    }
}

extern "C" void kernel_launch(void* const* d_in, const int* in_sizes, int n_in,
                              void* d_out, int out_size, void* d_ws, size_t ws_size,
                              hipStream_t stream)
{
    (void)in_sizes; (void)n_in;
    const float* phases = (const float*)d_in[0];
    float* outf = (float*)d_out;

    const size_t tabBytes = (size_t)STEPS * NN * sizeof(float2); // 4 MB each
    const bool useTables = (d_ws != nullptr) && (ws_size >= 2 * tabBytes);

    if (useTables) {
        float2* ca_tab = (float2*)d_ws;
        float2* cb_tab = (float2*)((char*)d_ws + tabBytes);
        hipLaunchKernelGGL(precompute_consts,
                           dim3((STEPS * NN + 255) / 256), dim3(256), 0, stream,
                           phases, ca_tab, cb_tab);
        hipLaunchKernelGGL(clements_split, dim3(NN), dim3(256), 0, stream,
                           phases, ca_tab, cb_tab, outf, out_size);
    } else {
        hipLaunchKernelGGL(clements_inline, dim3(NN), dim3(64), 0, stream,
                           phases, outf, out_size);
    }
}

// Round 12
// 455.211 us; speedup vs baseline: 2.2171x; 1.0891x over previous
//
#include <hip/hip_runtime.h>

#define NN    1024
#define STEPS 512

// packed-fp32 complex: f2 = (re, im), forced onto v_pk_* VOP3P with op_sel/neg
typedef float f2 __attribute__((ext_vector_type(2)));

// u + i*v = (u.x - v.y, u.y + v.x) : ONE v_pk_fma_f32
__device__ __forceinline__ f2 addi(f2 u, f2 v) {
    f2 d;
    asm("v_pk_fma_f32 %0, %1, 1.0, %2 op_sel:[1,0,0] op_sel_hi:[0,1,1] neg_lo:[0,1,0]"
        : "=v"(d) : "v"(v), "v"(u));
    return d;
}
// p*q : v_pk_mul + v_pk_fma (swizzles/negs in modifiers)
__device__ __forceinline__ f2 cmul(f2 p, f2 q) {
    f2 t, d;
    asm("v_pk_mul_f32 %0, %1, %2 op_sel:[1,1] op_sel_hi:[1,0] neg_lo:[1,0]"
        : "=v"(t) : "v"(p), "v"(q));
    asm("v_pk_fma_f32 %0, %1, %2, %3 op_sel_hi:[0,1,1]"
        : "=v"(d) : "v"(p), "v"(q), "v"(t));
    return d;
}

// ========== precompute per-row step constants ==========
// ca_tab[s][r] = 0.5 e^{i pa_s[r]};  cb_tab[s][r] = (r==0||r==N-1 ? 1 : 0.5) e^{i pb_s[r]}
__global__ void precompute_consts(const float* __restrict__ phases,
                                  float2* __restrict__ ca_tab,
                                  float2* __restrict__ cb_tab)
{
    int idx = blockIdx.x * blockDim.x + threadIdx.x;
    if (idx >= STEPS * NN) return;
    int s = idx >> 10;
    int r = idx & (NN - 1);
    float pa = phases[(size_t)(1 + 2 * s) * NN + r];
    float pb = phases[(size_t)(2 + 2 * s) * NN + r];
    float sa, cA, sb, cB;
    __sincosf(pa, &sa, &cA);
    __sincosf(pb, &sb, &cB);
    ca_tab[idx] = make_float2(0.5f * cA, 0.5f * sa);
    float sc = (r == 0 || r == NN - 1) ? 1.0f : 0.5f;
    cb_tab[idx] = make_float2(sc * cB, sc * sb);
}

// ---------- loads ----------
__device__ __forceinline__ void load4(const float2* __restrict__ p, f2 (&d)[4])
{
    const float4* p4 = reinterpret_cast<const float4*>(p);  // 32B-aligned (r0 multiple of 4)
    float4 v0 = p4[0], v1 = p4[1];
    d[0] = (f2){v0.x, v0.y}; d[1] = (f2){v0.z, v0.w};
    d[2] = (f2){v1.x, v1.y}; d[3] = (f2){v1.z, v1.w};
}
__device__ __forceinline__ f2 ldf2(const float2* __restrict__ p)
{
    float2 v = *p; return (f2){v.x, v.y};
}

// ---------- one step, 4 rows/lane, ONE barrier, zero-halo edges ----------
// Halo algebra: odd1 pair (r0+3, r0+4): m3' = m3 + i*nb ; m0'_next = nb + i*m3.
// odd2's halo is derived locally: u0_next = cbn*(nb + i*m3pre), u3_prev = cbp*(pv + i*m0pre).
// Edge rows 0/1023 use ZERO halo values so all merges are unconditional addi.
__device__ __forceinline__ void do_step4(f2 (&m)[4],
                                         const f2 (&ca)[4], const f2 (&cb)[4],
                                         f2 cbn, f2 cbp,
                                         int w, int t,
                                         f2* __restrict__ lo1, f2* __restrict__ hi1)
{
    // even1 (unscaled): lane-internal pairs (0,1) (2,3)
    { f2 a = m[0], b = m[1]; m[0] = addi(a, b); m[1] = addi(b, a); }
    { f2 a = m[2], b = m[3]; m[2] = addi(a, b); m[3] = addi(b, a); }
    // heater(pa) + even2 (scales folded into ca)
    { f2 u = cmul(ca[0], m[0]), v = cmul(ca[1], m[1]); m[0] = addi(u, v); m[1] = addi(v, u); }
    { f2 u = cmul(ca[2], m[2]), v = cmul(ca[3], m[3]); m[2] = addi(u, v); m[3] = addi(v, u); }

    // single cross-wave exchange of pre-odd1 boundary values
    if (t == 0)  lo1[w] = m[0];
    if (t == 63) hi1[w] = m[3];
    __syncthreads();

    f2 nb, pv;
    nb.x = __shfl_down(m[0].x, 1); nb.y = __shfl_down(m[0].y, 1);
    pv.x = __shfl_up  (m[3].x, 1); pv.y = __shfl_up  (m[3].y, 1);
    if (t == 63) nb = (w < 3) ? lo1[w + 1] : (f2){0.f, 0.f};  // row 1023: zero halo
    if (t == 0)  pv = (w > 0) ? hi1[w - 1] : (f2){0.f, 0.f};  // row 0: zero halo

    f2 m0pre = m[0], m3pre = m[3];

    // odd1 (unconditional merges; zero halo = passthrough)
    { f2 a = m[1], b = m[2]; m[1] = addi(a, b); m[2] = addi(b, a); }
    m[3] = addi(m[3], nb);
    m[0] = addi(m[0], pv);

    // heater(pb) + odd2 (scales folded into cb)
    f2 u0 = cmul(cb[0], m[0]);
    f2 u3 = cmul(cb[3], m[3]);
    f2 vn, up;
    vn.x = __shfl_down(u0.x, 1); vn.y = __shfl_down(u0.y, 1);
    up.x = __shfl_up  (u3.x, 1); up.y = __shfl_up  (u3.y, 1);
    if (t == 63) vn = (w < 3) ? cmul(cbn, addi(nb, m3pre)) : (f2){0.f, 0.f};
    if (t == 0)  up = (w > 0) ? cmul(cbp, addi(pv, m0pre)) : (f2){0.f, 0.f};
    { f2 u = cmul(cb[1], m[1]), v = cmul(cb[2], m[2]); m[1] = addi(u, v); m[2] = addi(v, u); }
    m[3] = addi(u3, vn);
    m[0] = addi(u0, up);
}

// ========== main: 1 block (4 waves) per column, 4 rows/lane ==========
__global__ void __launch_bounds__(256, 4)
clements_split(const float* __restrict__ phases,
               const float2* __restrict__ ca_tab,
               const float2* __restrict__ cb_tab,
               float* __restrict__ outf, int out_size)
{
    const int c   = blockIdx.x;
    const int tid = threadIdx.x;
    const int w   = tid >> 6;
    const int t   = tid & 63;
    const int r0  = tid << 2;      // = w*256 + t*4

    __shared__ f2 lo1[2][4], hi1[2][4];   // parity-double-buffered exchange slots

    const bool wantN = (t == 63 && w < 3);   // needs next-wave constant
    const bool wantP = (t == 0  && w > 0);   // needs prev-wave constant

    // M0 = heater(I, phases[0]): diagonal
    f2 m[4];
    {
        float sv, cv; __sincosf(phases[c], &sv, &cv);
        const f2 diag = {cv, sv};
#pragma unroll
        for (int j = 0; j < 4; ++j)
            m[j] = (r0 + j == c) ? diag : (f2){0.f, 0.f};
    }

    // register double-buffered constants; sched_barrier pins issue-early
    f2 caA[4], cbA[4], caB[4], cbB[4];
    f2 cbnA = {1.f, 0.f}, cbpA = {1.f, 0.f}, cbnB = {1.f, 0.f}, cbpB = {1.f, 0.f};
    load4(ca_tab + r0, caA);
    load4(cb_tab + r0, cbA);
    if (wantN) cbnA = ldf2(cb_tab + r0 + 4);
    if (wantP) cbpA = ldf2(cb_tab + r0 - 1);

    for (int s = 0; s < STEPS; s += 2) {
        {
            size_t o1 = (size_t)(s + 1) * NN + r0;
            load4(ca_tab + o1, caB);
            load4(cb_tab + o1, cbB);
            if (wantN) cbnB = ldf2(cb_tab + o1 + 4);
            if (wantP) cbpB = ldf2(cb_tab + o1 - 1);
        }
        __builtin_amdgcn_sched_barrier(0);
        do_step4(m, caA, cbA, cbnA, cbpA, w, t, lo1[0], hi1[0]);

        {
            int s2 = (s + 2 < STEPS) ? (s + 2) : 0;   // clamped; unused on last iter
            size_t o2 = (size_t)s2 * NN + r0;
            load4(ca_tab + o2, caA);
            load4(cb_tab + o2, cbA);
            if (wantN) cbnA = ldf2(cb_tab + o2 + 4);
            if (wantP) cbpA = ldf2(cb_tab + o2 - 1);
        }
        __builtin_amdgcn_sched_barrier(0);
        do_step4(m, caB, cbB, cbnB, cbpB, w, t, lo1[1], hi1[1]);
    }

    // final heater, store REAL PART float32, row-major [N][N], guarded
    const float* pf = phases + (size_t)(NN + 1) * NN + r0;
#pragma unroll
    for (int j = 0; j < 4; ++j) {
        float sf, cf; __sincosf(pf[j], &sf, &cf);
        f2 r = cmul((f2){cf, sf}, m[j]);
        int idx = (r0 + j) * NN + c;
        if (idx < out_size) outf[idx] = r.x;
    }
}

// ========== fallback (no workspace): R=16 inline kernel ==========
__device__ __forceinline__ void do_step16(f2 (&m)[16], const f2 (&ca)[16],
                                          const f2 (&cb)[16], int t)
{
#pragma unroll
    for (int j = 0; j < 16; j += 2) {
        f2 a = m[j], b = m[j + 1];
        m[j] = addi(a, b); m[j + 1] = addi(b, a);
    }
#pragma unroll
    for (int j = 0; j < 16; j += 2) {
        f2 u = cmul(ca[j], m[j]), v = cmul(ca[j + 1], m[j + 1]);
        m[j] = addi(u, v); m[j + 1] = addi(v, u);
    }
    f2 nb, pv;
    nb.x = __shfl_down(m[0].x, 1);  nb.y = __shfl_down(m[0].y, 1);
    pv.x = __shfl_up(m[15].x, 1);   pv.y = __shfl_up(m[15].y, 1);
    if (t == 63) nb = (f2){0.f, 0.f};
    if (t == 0)  pv = (f2){0.f, 0.f};
#pragma unroll
    for (int j = 1; j < 15; j += 2) {
        f2 a = m[j], b = m[j + 1];
        m[j] = addi(a, b); m[j + 1] = addi(b, a);
    }
    m[15] = addi(m[15], nb);
    m[0]  = addi(m[0], pv);
    f2 u0 = cmul(cb[0], m[0]), u15 = cmul(cb[15], m[15]);
    f2 vn, up;
    vn.x = __shfl_down(u0.x, 1);  vn.y = __shfl_down(u0.y, 1);
    up.x = __shfl_up(u15.x, 1);   up.y = __shfl_up(u15.y, 1);
    if (t == 63) vn = (f2){0.f, 0.f};
    if (t == 0)  up = (f2){0.f, 0.f};
#pragma unroll
    for (int j = 1; j < 15; j += 2) {
        f2 u = cmul(cb[j], m[j]), v = cmul(cb[j + 1], m[j + 1]);
        m[j] = addi(u, v); m[j + 1] = addi(v, u);
    }
    m[15] = addi(u15, vn);
    m[0]  = addi(u0, up);
}

__global__ void __launch_bounds__(64, 1)
clements_inline(const float* __restrict__ phases,
                float* __restrict__ outf, int out_size)
{
    const int c = blockIdx.x, t = threadIdx.x, r0 = t * 16;
    f2 m[16];
    {
        float sv, cv; __sincosf(phases[c], &sv, &cv);
        const f2 diag = {cv, sv};
#pragma unroll
        for (int j = 0; j < 16; ++j)
            m[j] = (r0 + j == c) ? diag : (f2){0.f, 0.f};
    }
    for (int s = 0; s < STEPS; ++s) {
        const float* pa = phases + (size_t)(1 + 2 * s) * NN + r0;
        const float* pb = pa + NN;
        f2 ca[16], cb[16];
#pragma unroll
        for (int q = 0; q < 4; ++q) {
            float4 va = reinterpret_cast<const float4*>(pa)[q];
            float4 vb = reinterpret_cast<const float4*>(pb)[q];
            float s0, c0;
            __sincosf(va.x, &s0, &c0); ca[4*q+0] = (f2){0.5f*c0, 0.5f*s0};
            __sincosf(va.y, &s0, &c0); ca[4*q+1] = (f2){0.5f*c0, 0.5f*s0};
            __sincosf(va.z, &s0, &c0); ca[4*q+2] = (f2){0.5f*c0, 0.5f*s0};
            __sincosf(va.w, &s0, &c0); ca[4*q+3] = (f2){0.5f*c0, 0.5f*s0};
            __sincosf(vb.x, &s0, &c0); cb[4*q+0] = (f2){0.5f*c0, 0.5f*s0};
            __sincosf(vb.y, &s0, &c0); cb[4*q+1] = (f2){0.5f*c0, 0.5f*s0};
            __sincosf(vb.z, &s0, &c0); cb[4*q+2] = (f2){0.5f*c0, 0.5f*s0};
            __sincosf(vb.w, &s0, &c0); cb[4*q+3] = (f2){0.5f*c0, 0.5f*s0};
        }
        if (t == 0)  cb[0]  = 2.f * cb[0];
        if (t == 63) cb[15] = 2.f * cb[15];
        do_step16(m, ca, cb, t);
    }
    const float* pf = phases + (size_t)(NN + 1) * NN + r0;
#pragma unroll
    for (int j = 0; j < 16; ++j) {
        float sf, cf; __sincosf(pf[j], &sf, &cf);
        f2 r = cmul((f2){cf, sf}, m[j]);
        int idx = (r0 + j) * NN + c;
        if (idx < out_size) outf[idx] = r.x;
    }
}

extern "C" void kernel_launch(void* const* d_in, const int* in_sizes, int n_in,
                              void* d_out, int out_size, void* d_ws, size_t ws_size,
                              hipStream_t stream)
{
    (void)in_sizes; (void)n_in;
    const float* phases = (const float*)d_in[0];
    float* outf = (float*)d_out;

    const size_t tabBytes = (size_t)STEPS * NN * sizeof(float2); // 4 MB each
    const bool useTables = (d_ws != nullptr) && (ws_size >= 2 * tabBytes);

    if (useTables) {
        float2* ca_tab = (float2*)d_ws;
        float2* cb_tab = (float2*)((char*)d_ws + tabBytes);
        hipLaunchKernelGGL(precompute_consts,
                           dim3((STEPS * NN + 255) / 256), dim3(256), 0, stream,
                           phases, ca_tab, cb_tab);
        hipLaunchKernelGGL(clements_split, dim3(NN), dim3(256), 0, stream,
                           phases, ca_tab, cb_tab, outf, out_size);
    } else {
        hipLaunchKernelGGL(clements_inline, dim3(NN), dim3(64), 0, stream,
                           phases, outf, out_size);
    }
}